// Round 1
// 729.111 us; speedup vs baseline: 1.4751x; 1.4751x over previous
//
#include <hip/hip_runtime.h>
#include <stdint.h>

// ---------------------------------------------------------------------------
// Decoder: GRU(seq) + attention + dense + vocab projection
// H=512, V=32000, B=16, Td=Te=64
// Round 5:
//  - GRU restructured into 16 INDEPENDENT per-batch gangs (batches don't
//    interact in the recurrence). 256 blocks x 512 threads; gang b = blocks
//    [16b,16b+16). Barrier is now per-gang over 16 blocks via a 16-slot
//    flag cache line (store-own-slot + poll-all, no serialized atomic RMW
//    chain, one fewer LLC hop than counter+go).
//    Round-4 profile: 128-block global barrier = ~10.2 us/step x 64 steps.
//  - All former fp32 GEMMs -> split-bf16 MFMA (A=Ah+Al, B=Bh+Bl, compute
//    AhBh+AhBl+AlBh, fp32 accumulate): ~1.6e-5 relative error, MFMA rate.
//  - cat matrix stored as hi/lo bf16 pairs written directly by GRU/attn.
// ---------------------------------------------------------------------------

#define Hdim 512
#define Vdim 32000
#define Bdim 16
#define Tdim 64
#define BT   1024   // B*Td rows
#define GANG_BLOCKS 16

typedef __attribute__((ext_vector_type(8))) short bf16x8;
typedef __attribute__((ext_vector_type(4))) float f32x4;

static __device__ __forceinline__ unsigned short f2bf(float f) {
    unsigned u = __float_as_uint(f);
    u = u + 0x7FFFu + ((u >> 16) & 1u);   // RNE
    return (unsigned short)(u >> 16);
}
static __device__ __forceinline__ float bf2f(unsigned short h) {
    return __uint_as_float((unsigned)h << 16);
}

// --------------------------- small utility kernels -------------------------

__global__ void zero_kernel(float* p, int n) {
    int i = blockIdx.x * 256 + threadIdx.x;
    if (i < n) p[i] = 0.f;
}

// vectorized f32 -> bf16 (n % 4 == 0)
__global__ void f32_to_bf16_kernel(const float* __restrict__ in,
                                   unsigned short* __restrict__ out, int n) {
    int i = (blockIdx.x * 256 + threadIdx.x) * 4;
    int stride = gridDim.x * 256 * 4;
    for (; i < n; i += stride) {
        float4 v = *(const float4*)(in + i);
        unsigned short h[4] = {f2bf(v.x), f2bf(v.y), f2bf(v.z), f2bf(v.w)};
        *(uint2*)(out + i) = *(const uint2*)h;
    }
}

// f32 -> (hi bf16, lo bf16) split (n % 4 == 0)
__global__ void split_bf16_kernel(const float* __restrict__ in,
                                  unsigned short* __restrict__ hi,
                                  unsigned short* __restrict__ lo, int n) {
    int i = (blockIdx.x * 256 + threadIdx.x) * 4;
    int stride = gridDim.x * 256 * 4;
    for (; i < n; i += stride) {
        float4 v = *(const float4*)(in + i);
        float f[4] = {v.x, v.y, v.z, v.w};
        unsigned short h[4], l[4];
#pragma unroll
        for (int k = 0; k < 4; ++k) {
            h[k] = f2bf(f[k]);
            l[k] = f2bf(f[k] - bf2f(h[k]));
        }
        *(uint2*)(hi + i) = *(const uint2*)h;
        *(uint2*)(lo + i) = *(const uint2*)l;
    }
}

// ----------------------- split-bf16 MFMA GEMM ------------------------------
// C[M x N] = act( A @ B^T + bias ),  A ~ (Ah+Al) (M x K, lda elements),
// B ~ (Bh+Bl) (N x K, ldb). M,N % 128 == 0, K % 32 == 0.
// acc = Ah*Bh + Ah*Bl + Al*Bh  (Al*Bl dropped, ~1e-5 rel).
// If Cb != null, write bf16 to Cb instead of fp32 to C.
// grid = (N/128, M/128), block = 256.

__global__ __launch_bounds__(256) void gemm_split(
    const unsigned short* __restrict__ Ah, const unsigned short* __restrict__ Al, int lda,
    const unsigned short* __restrict__ Bh, const unsigned short* __restrict__ Bl, int ldb,
    const float* __restrict__ bias,
    float* __restrict__ C, unsigned short* __restrict__ Cb, int ldc,
    int K, int act)
{
    __shared__ unsigned short AsH[128 * 40];
    __shared__ unsigned short AsL[128 * 40];
    __shared__ unsigned short BsH[128 * 40];
    __shared__ unsigned short BsL[128 * 40];
    const int tid = threadIdx.x;
    const int m0 = blockIdx.y * 128, n0 = blockIdx.x * 128;
    const int wave = tid >> 6, lane = tid & 63;
    const int wm = (wave >> 1) * 64, wn = (wave & 1) * 64;
    const int lrow = lane & 15, lk = (lane >> 4) * 8;

    f32x4 acc[4][4];
#pragma unroll
    for (int i = 0; i < 4; ++i)
#pragma unroll
        for (int j = 0; j < 4; ++j) acc[i][j] = (f32x4){0.f, 0.f, 0.f, 0.f};

    for (int k0 = 0; k0 < K; k0 += 32) {
#pragma unroll
        for (int i = 0; i < 2; ++i) {
            int idx = tid + i * 256;        // 0..511
            int rr = idx >> 2, kq = (idx & 3) * 8;
            size_t ao = (size_t)(m0 + rr) * lda + k0 + kq;
            size_t bo = (size_t)(n0 + rr) * ldb + k0 + kq;
            *(uint4*)(&AsH[rr * 40 + kq]) = *(const uint4*)(Ah + ao);
            *(uint4*)(&AsL[rr * 40 + kq]) = *(const uint4*)(Al + ao);
            *(uint4*)(&BsH[rr * 40 + kq]) = *(const uint4*)(Bh + bo);
            *(uint4*)(&BsL[rr * 40 + kq]) = *(const uint4*)(Bl + bo);
        }
        __syncthreads();
        bf16x8 ah[4], al[4], bh[4], bl[4];
#pragma unroll
        for (int i = 0; i < 4; ++i) {
            ah[i] = *(const bf16x8*)(&AsH[(wm + i * 16 + lrow) * 40 + lk]);
            al[i] = *(const bf16x8*)(&AsL[(wm + i * 16 + lrow) * 40 + lk]);
        }
#pragma unroll
        for (int j = 0; j < 4; ++j) {
            bh[j] = *(const bf16x8*)(&BsH[(wn + j * 16 + lrow) * 40 + lk]);
            bl[j] = *(const bf16x8*)(&BsL[(wn + j * 16 + lrow) * 40 + lk]);
        }
#pragma unroll
        for (int i = 0; i < 4; ++i)
#pragma unroll
            for (int j = 0; j < 4; ++j) {
                acc[i][j] = __builtin_amdgcn_mfma_f32_16x16x32_bf16(ah[i], bh[j], acc[i][j], 0, 0, 0);
                acc[i][j] = __builtin_amdgcn_mfma_f32_16x16x32_bf16(ah[i], bl[j], acc[i][j], 0, 0, 0);
                acc[i][j] = __builtin_amdgcn_mfma_f32_16x16x32_bf16(al[i], bh[j], acc[i][j], 0, 0, 0);
            }
        __syncthreads();
    }

    const int crow = m0 + wm + ((lane >> 4) * 4);
    const int ccol = n0 + wn + (lane & 15);
#pragma unroll
    for (int i = 0; i < 4; ++i) {
#pragma unroll
        for (int j = 0; j < 4; ++j) {
            int col = ccol + j * 16;
            float bv = bias[col];
#pragma unroll
            for (int rr = 0; rr < 4; ++rr) {
                int row = crow + i * 16 + rr;
                float v = acc[i][j][rr] + bv;
                if (act == 1) v = tanhf(v);
                if (Cb) Cb[(size_t)row * ldc + col] = f2bf(v);
                else    C [(size_t)row * ldc + col] = v;
            }
        }
    }
}

// --------------------------- persistent GRU --------------------------------
// 16 independent gangs (one per batch) x 16 blocks x 512 threads.
// Gang b = blocks [16b, 16b+16). Block blk owns hidden units
// j0 = blk*32 .. +31 (8 waves x 4 units; 12 W_hh rows per wave in regs).
// h exchanged via relaxed agent-scope loads/stores, ping-pong hbuf.
// Per-gang barrier: 16-slot flag line (sync[b*64 + blk]); each block's tid0
// stores t+1 to its slot after s_waitcnt(0)+__syncthreads; wave 0 polls all
// 16 slots with agent-scope loads. Monotone flags -> no reset needed.

static __device__ __forceinline__ void agent_st(float* p, float v) {
    __hip_atomic_store(p, v, __ATOMIC_RELAXED, __HIP_MEMORY_SCOPE_AGENT);
}

__global__ __launch_bounds__(512) void gru_persistent(
    const float* __restrict__ xp,        // (1024,1536) rows = b*64+t
    const float* __restrict__ Whh,       // (1536,512)
    const float* __restrict__ bhh,       // (1536)
    const int*   __restrict__ lengths,   // (16)
    float* __restrict__ hbuf,            // (2,16,512); zero-initialized
    int*   __restrict__ sync,            // 1024 ints; gang b flags at [b*64 .. +15]
    unsigned short* __restrict__ cath,   // (1024,1024) cols [0,512)
    unsigned short* __restrict__ catl,
    float* __restrict__ h_last)          // (16,512)
{
    const int bid  = blockIdx.x;
    const int b    = bid >> 4;           // gang = batch
    const int blk  = bid & 15;
    const int tid  = threadIdx.x;
    const int wave = tid >> 6, lane = tid & 63;
    const int j0 = blk * 32 + wave * 4;  // this wave's 4 hidden units
    const int k0 = lane * 8;

    // --- W_hh slice into registers (once): 12 rows x 8 k-elems ---
    float w[12][8];
#pragma unroll
    for (int g = 0; g < 3; ++g)
#pragma unroll
        for (int jj = 0; jj < 4; ++jj) {
            const float* src = Whh + (size_t)(g * 512 + j0 + jj) * Hdim + k0;
            float4 a = *(const float4*)src;
            float4 bq = *(const float4*)(src + 4);
            int r = g * 4 + jj;
            w[r][0] = a.x;  w[r][1] = a.y;  w[r][2] = a.z;  w[r][3] = a.w;
            w[r][4] = bq.x; w[r][5] = bq.y; w[r][6] = bq.z; w[r][7] = bq.w;
        }

    const int j = j0 + (lane & 3);       // output unit for lanes 0..3
    float bh_r = 0.f, bh_z = 0.f, bh_n = 0.f;
    if (lane < 4) {
        bh_r = bhh[j]; bh_z = bhh[512 + j]; bh_n = bhh[1024 + j];
    }
    const int len_b = lengths[b];
    float hprev = 0.f;                   // this lane's own h[b][j] (h0 = 0)

    int* flags = sync + b * 64;          // 16 slots, one 256B region per gang
    const float* xbase = xp + (size_t)b * Tdim * 1536;

    for (int t = 0; t < Tdim; ++t) {
        const float* hcur = hbuf + (t & 1) * (Bdim * Hdim) + b * Hdim;
        float*       hnxt = hbuf + ((t + 1) & 1) * (Bdim * Hdim) + b * Hdim;

        // xp loads are independent of h -> issue early
        float xr = 0.f, xz = 0.f, xn = 0.f;
        if (lane < 4) {
            const float* xrow = xbase + (size_t)t * 1536;
            xr = xrow[j]; xz = xrow[512 + j]; xn = xrow[1024 + j];
        }

        // h (512 floats for this batch): 8 elems per lane
        const unsigned long long* hp = (const unsigned long long*)(hcur + k0);
        float hv[8];
#pragma unroll
        for (int q = 0; q < 4; ++q) {
            unsigned long long u =
                __hip_atomic_load(hp + q, __ATOMIC_RELAXED, __HIP_MEMORY_SCOPE_AGENT);
            union { unsigned long long u; float f[2]; } cv; cv.u = u;
            hv[q * 2]     = cv.f[0];
            hv[q * 2 + 1] = cv.f[1];
        }

        float p[12];
#pragma unroll
        for (int r = 0; r < 12; ++r) {
            float s = 0.f;
#pragma unroll
            for (int k = 0; k < 8; ++k) s += w[r][k] * hv[k];
            p[r] = s;
        }

        // butterfly reduce across 64 lanes
#pragma unroll
        for (int off = 1; off < 64; off <<= 1)
#pragma unroll
            for (int r = 0; r < 12; ++r)
                p[r] += __shfl_xor(p[r], off);

        if (lane < 4) {
            const int jj = lane;
            float hr = p[jj]     + bh_r;
            float hz = p[4 + jj] + bh_z;
            float hn = p[8 + jj] + bh_n;
            float rg = 1.f / (1.f + __expf(-(xr + hr)));
            float zg = 1.f / (1.f + __expf(-(xz + hz)));
            float ng = tanhf(xn + rg * hn);
            float hnew = (1.f - zg) * ng + zg * hprev;
            bool valid = t < len_b;
            float hkeep = valid ? hnew : hprev;
            hprev = hkeep;
            agent_st(hnxt + j, hkeep);
            float y = valid ? hnew : 0.f;
            unsigned short yh = f2bf(y);
            size_t ci = (size_t)(b * Tdim + t) * 1024 + j;
            cath[ci] = yh;
            catl[ci] = f2bf(y - bf2f(yh));
            if (t == Tdim - 1) h_last[b * Hdim + j] = hkeep;
        }

        // ---- per-gang barrier (16-slot flag line, store-own/poll-all) ----
        if (t == Tdim - 1) break;
        __asm__ volatile("" ::: "memory");
        __builtin_amdgcn_s_waitcnt(0);     // drain this wave's agent stores
        __asm__ volatile("" ::: "memory");
        __syncthreads();                   // whole block drained
        if (wave == 0) {
            if (lane == 0)
                __hip_atomic_store(&flags[blk], t + 1, __ATOMIC_RELAXED,
                                   __HIP_MEMORY_SCOPE_AGENT);
            for (;;) {
                int v = t + 1;
                if (lane < GANG_BLOCKS)
                    v = __hip_atomic_load(&flags[lane], __ATOMIC_RELAXED,
                                          __HIP_MEMORY_SCOPE_AGENT);
                if (__all(v >= t + 1)) break;
                __builtin_amdgcn_s_sleep(1);
            }
        }
        __syncthreads();
        __asm__ volatile("" ::: "memory");
    }
}

// ------------------------------ attention ----------------------------------
// one block per (b,d); writes context to cat cols [512,1024) as hi/lo bf16

__global__ __launch_bounds__(256) void attn_kernel(
    const float* __restrict__ encp,     // (1024,512)
    const float* __restrict__ decp,     // (1024,512)
    const float* __restrict__ enc,      // (16,64,512)
    const float* __restrict__ battn,    // (512)
    const float* __restrict__ vw,       // (512)
    const float* __restrict__ vb,       // (1)
    const int* __restrict__ enc_len,    // (16)
    const int* __restrict__ dec_len,    // (16)
    unsigned short* __restrict__ cath,
    unsigned short* __restrict__ catl)
{
    const int blk = blockIdx.x;
    const int b = blk >> 6, d = blk & 63;
    const int tid = threadIdx.x;
    const size_t obase = (size_t)(b * Tdim + d) * 1024 + 512;

    if (d >= dec_len[b]) {
        for (int h = tid; h < Hdim; h += 256) { cath[obase + h] = 0; catl[obase + h] = 0; }
        return;
    }
    const int Tv = enc_len[b];

    __shared__ float part[64][4];
    __shared__ float a_lds[64];

    const int e = tid >> 2, p = tid & 3;
    float s = 0.f;
    if (e < Tv) {
        const float* ep = encp + (size_t)(b * Tdim + e) * Hdim;
        const float* dp = decp + (size_t)(b * Tdim + d) * Hdim;
        const int g0 = p * 128;
        for (int g = g0; g < g0 + 128; ++g)
            s += vw[g] * tanhf(ep[g] + dp[g] + battn[g]);
    }
    part[e][p] = s;
    __syncthreads();

    if (tid < 64) {
        const int e2 = tid;
        float en = (e2 < Tv) ? (part[e2][0] + part[e2][1] + part[e2][2] + part[e2][3] + vb[0]) : -1e30f;
        float m = en;
#pragma unroll
        for (int off = 32; off; off >>= 1) m = fmaxf(m, __shfl_xor(m, off));
        float ex = (e2 < Tv) ? __expf(en - m) : 0.f;
        float sum = ex;
#pragma unroll
        for (int off = 32; off; off >>= 1) sum += __shfl_xor(sum, off);
        a_lds[e2] = ex / sum;
    }
    __syncthreads();

    const int h = tid * 2;
    float c0 = 0.f, c1 = 0.f;
    for (int e3 = 0; e3 < Tv; ++e3) {
        float a = a_lds[e3];
        float2 ev = *(const float2*)(enc + (size_t)(b * Tdim + e3) * Hdim + h);
        c0 += a * ev.x; c1 += a * ev.y;
    }
    unsigned short h0 = f2bf(c0), h1 = f2bf(c1);
    cath[obase + h]     = h0;  catl[obase + h]     = f2bf(c0 - bf2f(h0));
    cath[obase + h + 1] = h1;  catl[obase + h + 1] = f2bf(c1 - bf2f(h1));
}

// --------------------------- logits bf16 MFMA GEMM -------------------------
// C(1024 x 32000) = A(1024x512 bf16) @ B(32000x512 bf16)^T + bias, fp32 out

__global__ __launch_bounds__(256) void gemm_logits(
    const unsigned short* __restrict__ A,
    const unsigned short* __restrict__ B,
    const float* __restrict__ bias,
    float* __restrict__ C)
{
    const int K = Hdim;
    __shared__ unsigned short As[128 * 40];
    __shared__ unsigned short Bs[128 * 40];
    const int tid = threadIdx.x;
    const int m0 = blockIdx.y * 128, n0 = blockIdx.x * 128;
    const int wave = tid >> 6, lane = tid & 63;
    const int wm = (wave >> 1) * 64, wn = (wave & 1) * 64;
    const int lrow = lane & 15, lk = (lane >> 4) * 8;

    f32x4 acc[4][4];
#pragma unroll
    for (int i = 0; i < 4; ++i)
#pragma unroll
        for (int j = 0; j < 4; ++j) acc[i][j] = (f32x4){0.f, 0.f, 0.f, 0.f};

    for (int k0 = 0; k0 < K; k0 += 32) {
#pragma unroll
        for (int i = 0; i < 2; ++i) {
            int idx = tid + i * 256;        // 0..511
            int rr = idx >> 2, kq = (idx & 3) * 8;
            *(uint4*)(&As[rr * 40 + kq]) = *(const uint4*)(A + (size_t)(m0 + rr) * K + k0 + kq);
            *(uint4*)(&Bs[rr * 40 + kq]) = *(const uint4*)(B + (size_t)(n0 + rr) * K + k0 + kq);
        }
        __syncthreads();
        bf16x8 af[4], bf[4];
#pragma unroll
        for (int i = 0; i < 4; ++i) af[i] = *(const bf16x8*)(&As[(wm + i * 16 + lrow) * 40 + lk]);
#pragma unroll
        for (int j = 0; j < 4; ++j) bf[j] = *(const bf16x8*)(&Bs[(wn + j * 16 + lrow) * 40 + lk]);
#pragma unroll
        for (int i = 0; i < 4; ++i)
#pragma unroll
            for (int j = 0; j < 4; ++j)
                acc[i][j] = __builtin_amdgcn_mfma_f32_16x16x32_bf16(af[i], bf[j], acc[i][j], 0, 0, 0);
        __syncthreads();
    }

    const int crow = m0 + wm + ((lane >> 4) * 4);
    const int ccol = n0 + wn + (lane & 15);
#pragma unroll
    for (int i = 0; i < 4; ++i) {
#pragma unroll
        for (int j = 0; j < 4; ++j) {
            int col = ccol + j * 16;
            float bv = bias[col];
#pragma unroll
            for (int rr = 0; rr < 4; ++rr) {
                int row = crow + i * 16 + rr;
                C[(size_t)row * Vdim + col] = acc[i][j][rr] + bv;
            }
        }
    }
}

// ------------------------------- launcher ----------------------------------

extern "C" void kernel_launch(void* const* d_in, const int* in_sizes, int n_in,
                              void* d_out, int out_size, void* d_ws, size_t ws_size,
                              hipStream_t stream) {
    (void)in_sizes; (void)n_in; (void)out_size; (void)ws_size;

    const float* input_seqs  = (const float*)d_in[0];
    const int*   input_len   = (const int*)  d_in[1];
    const float* enc_out     = (const float*)d_in[2];
    const int*   enc_len     = (const int*)  d_in[3];
    const float* W_ih        = (const float*)d_in[4];
    const float* W_hh        = (const float*)d_in[5];
    const float* b_ih        = (const float*)d_in[6];
    const float* b_hh        = (const float*)d_in[7];
    const float* W_attn      = (const float*)d_in[8];
    const float* b_attn      = (const float*)d_in[9];
    const float* v_w         = (const float*)d_in[10];
    const float* v_b         = (const float*)d_in[11];
    const float* W_dense     = (const float*)d_in[12];
    const float* b_dense     = (const float*)d_in[13];
    const float* W_out       = (const float*)d_in[14];
    const float* b_out       = (const float*)d_in[15];

    float* logits = (float*)d_out;                        // (1024, 32000)
    float* h_last = (float*)d_out + (size_t)BT * Vdim;    // (16, 512)

    // ---- workspace layout ----
    float* ws    = (float*)d_ws;
    float* xp    = ws;                         // 1572864 f
    float* encp  = xp   + 1572864;             // 524288 f
    float* decp  = encp + 524288;              // 524288 f
    float* hbuf  = decp + 524288;              // 16384 f
    float* zbias = hbuf + 16384;               // 512 f
    // sync lives in the decp region (dead until gemm step 6, after the GRU):
    int*   sync  = (int*)decp;                 // 1024 int (16 gangs x 64)
    unsigned short* U0 = (unsigned short*)(zbias + 512);
    unsigned short* inp_h   = U0;               // 524288
    unsigned short* inp_l   = U0 + 524288;      // 524288
    unsigned short* Wih_h   = U0 + 1048576;     // 786432
    unsigned short* Wih_l   = U0 + 1835008;     // 786432
    unsigned short* Wattn_h = U0 + 2621440;     // 524288
    unsigned short* Wattn_l = U0 + 3145728;     // 524288
    unsigned short* Wden_h  = U0 + 3670016;     // 524288
    unsigned short* Wden_l  = U0 + 4194304;     // 524288
    unsigned short* enc_h   = U0 + 4718592;     // 524288
    unsigned short* enc_l   = U0 + 5242880;     // 524288
    unsigned short* Wout_bf = U0 + 5767168;     // 16384000
    // cat hi/lo alias the inp/Wih splits (dead after x_proj):
    unsigned short* cath = U0;                  // 1048576 (1024x1024)
    unsigned short* catl = U0 + 1048576;        // 1048576
    // dense_bf aliases encp (dead after attn):
    unsigned short* dense_bf = (unsigned short*)encp;   // 524288

    // 1. zero hbuf + zbias (contiguous) and the gang-flag array
    zero_kernel<<<(16384 + 512 + 255) / 256, 256, 0, stream>>>(hbuf, 16384 + 512);
    zero_kernel<<<4, 256, 0, stream>>>((float*)sync, 1024);
    // 2. converts / splits
    f32_to_bf16_kernel<<<4096, 256, 0, stream>>>(W_out, Wout_bf, Vdim * Hdim);
    split_bf16_kernel<<<256, 256, 0, stream>>>(input_seqs, inp_h, inp_l, BT * Hdim);
    split_bf16_kernel<<<256, 256, 0, stream>>>(W_ih, Wih_h, Wih_l, 1536 * Hdim);
    split_bf16_kernel<<<256, 256, 0, stream>>>(W_attn, Wattn_h, Wattn_l, Hdim * 1024);
    split_bf16_kernel<<<256, 256, 0, stream>>>(W_dense, Wden_h, Wden_l, Hdim * 1024);
    split_bf16_kernel<<<256, 256, 0, stream>>>(enc_out, enc_h, enc_l, BT * Hdim);

    // 3. x_proj = input_seqs @ W_ih^T + b_ih   (1024 x 1536, K=512)
    gemm_split<<<dim3(1536 / 128, BT / 128), 256, 0, stream>>>(
        inp_h, inp_l, Hdim, Wih_h, Wih_l, Hdim, b_ih, xp, nullptr, 1536, Hdim, 0);

    // 4. enc_p = enc @ We^T  (We = W_attn[:, :512], ldb=1024), no bias
    gemm_split<<<dim3(Hdim / 128, BT / 128), 256, 0, stream>>>(
        enc_h, enc_l, Hdim, Wattn_h, Wattn_l, 1024, zbias, encp, nullptr, Hdim, Hdim, 0);

    // 5. GRU (16 per-batch gangs x 16 blocks x 512 thr; writes cat cols
    //    [0,512) as hi/lo bf16, h_last)
    gru_persistent<<<Bdim * GANG_BLOCKS, 512, 0, stream>>>(
        xp, W_hh, b_hh, input_len, hbuf, sync, cath, catl, h_last);

    // 6. dec_p = dec_out @ Wd^T (A = cat[:, :512] hi/lo, lda=1024), no bias
    gemm_split<<<dim3(Hdim / 128, BT / 128), 256, 0, stream>>>(
        cath, catl, 1024, Wattn_h + 512, Wattn_l + 512, 1024, zbias, decp, nullptr, Hdim, Hdim, 0);

    // 7. attention -> cat cols [512,1024) hi/lo bf16
    attn_kernel<<<BT, 256, 0, stream>>>(encp, decp, enc_out, b_attn, v_w, v_b,
                                        enc_len, input_len, cath, catl);

    // 8. dense = tanh(cat @ W_dense^T + b_dense) -> bf16 directly (K=1024)
    gemm_split<<<dim3(Hdim / 128, BT / 128), 256, 0, stream>>>(
        cath, catl, 1024, Wden_h, Wden_l, 1024, b_dense, nullptr, dense_bf, Hdim, 1024, 1);

    // 9. logits = dense @ W_out^T + b_out  (1024 x 32000, K=512)
    gemm_logits<<<dim3(Vdim / 128, BT / 128), 256, 0, stream>>>(
        dense_bf, Wout_bf, b_out, logits);
}

// Round 2
// 709.849 us; speedup vs baseline: 1.5151x; 1.0271x over previous
//
#include <hip/hip_runtime.h>
#include <stdint.h>

// ---------------------------------------------------------------------------
// Decoder: GRU(seq) + attention + dense + vocab projection
// H=512, V=32000, B=16, Td=Te=64
// Round 6:
//  - GRU: barrier ELIMINATED. h exchanged as tagged 8B atomics
//    (tag<<32|bits) in a parity double-buffered slot array; wave 0 of each
//    block polls the data itself (tag==t) and stages h into LDS; single
//    __syncthreads per step. Round-5 profile: flag-barrier chain was
//    4.4us/step (store-drain + flag hop + h load serialized).
//  - Preprocessing (zero + 5 hi/lo splits) merged into ONE kernel.
//  - W_out f32->bf16 conversion kernel deleted: gemm_logits converts
//    inline during LDS staging (saves 96MB HBM traffic + a dispatch).
//  - All former fp32 GEMMs -> split-bf16 MFMA (A=Ah+Al, B=Bh+Bl, compute
//    AhBh+AhBl+AlBh, fp32 accumulate): ~1.6e-5 relative error, MFMA rate.
// ---------------------------------------------------------------------------

#define Hdim 512
#define Vdim 32000
#define Bdim 16
#define Tdim 64
#define BT   1024   // B*Td rows
#define GANG_BLOCKS 16

typedef __attribute__((ext_vector_type(8))) short bf16x8;
typedef __attribute__((ext_vector_type(4))) float f32x4;

static __device__ __forceinline__ unsigned short f2bf(float f) {
    unsigned u = __float_as_uint(f);
    u = u + 0x7FFFu + ((u >> 16) & 1u);   // RNE
    return (unsigned short)(u >> 16);
}
static __device__ __forceinline__ float bf2f(unsigned short h) {
    return __uint_as_float((unsigned)h << 16);
}

// --------------------------- merged preprocessing --------------------------
// One kernel: zeroes hslots+zbias and does all five f32 -> (hi,lo) bf16
// splits. Unified float4-unit index space with compile-time segment bounds.

#define U_ZERO 8320      // (2*16*512 u64 -> 32768 f) + 512 f zbias, /4
#define U_INP  131072    // 1024*512/4
#define U_WIH  196608    // 1536*512/4
#define U_WAT  131072    // 512*1024/4
#define U_WDE  131072    // 512*1024/4
#define U_ENC  131072    // 1024*512/4
#define U_TOT  (U_ZERO + U_INP + U_WIH + U_WAT + U_WDE + U_ENC)  // 729216

__global__ __launch_bounds__(256) void preproc_kernel(
    const float* __restrict__ input_seqs,
    const float* __restrict__ W_ih,
    const float* __restrict__ W_attn,
    const float* __restrict__ W_dense,
    const float* __restrict__ enc,
    float* __restrict__ zero_base,      // hslots..zbias, 33280 floats
    unsigned short* __restrict__ inp_h, unsigned short* __restrict__ inp_l,
    unsigned short* __restrict__ Wih_h, unsigned short* __restrict__ Wih_l,
    unsigned short* __restrict__ Wat_h, unsigned short* __restrict__ Wat_l,
    unsigned short* __restrict__ Wde_h, unsigned short* __restrict__ Wde_l,
    unsigned short* __restrict__ enc_h, unsigned short* __restrict__ enc_l)
{
    int u = blockIdx.x * 256 + threadIdx.x;
    const int stride = gridDim.x * 256;
    for (; u < U_TOT; u += stride) {
        int r = u;
        if (r < U_ZERO) {
            float4 z; z.x = 0.f; z.y = 0.f; z.z = 0.f; z.w = 0.f;
            *(float4*)(zero_base + r * 4) = z;
            continue;
        }
        r -= U_ZERO;
        const float* src; unsigned short* hi; unsigned short* lo;
        if (r < U_INP) { src = input_seqs; hi = inp_h; lo = inp_l; }
        else { r -= U_INP;
            if (r < U_WIH) { src = W_ih; hi = Wih_h; lo = Wih_l; }
            else { r -= U_WIH;
                if (r < U_WAT) { src = W_attn; hi = Wat_h; lo = Wat_l; }
                else { r -= U_WAT;
                    if (r < U_WDE) { src = W_dense; hi = Wde_h; lo = Wde_l; }
                    else { r -= U_WDE; src = enc; hi = enc_h; lo = enc_l; }
                }
            }
        }
        int i = r * 4;
        float4 v = *(const float4*)(src + i);
        float f[4] = {v.x, v.y, v.z, v.w};
        unsigned short h[4], l[4];
#pragma unroll
        for (int k = 0; k < 4; ++k) {
            h[k] = f2bf(f[k]);
            l[k] = f2bf(f[k] - bf2f(h[k]));
        }
        *(uint2*)(hi + i) = *(const uint2*)h;
        *(uint2*)(lo + i) = *(const uint2*)l;
    }
}

// ----------------------- split-bf16 MFMA GEMM ------------------------------
// C[M x N] = act( A @ B^T + bias ),  A ~ (Ah+Al) (M x K, lda elements),
// B ~ (Bh+Bl) (N x K, ldb). M,N % 128 == 0, K % 32 == 0.
// acc = Ah*Bh + Ah*Bl + Al*Bh  (Al*Bl dropped, ~1e-5 rel).
// If Cb != null, write bf16 to Cb instead of fp32 to C.
// grid = (N/128, M/128), block = 256.

__global__ __launch_bounds__(256) void gemm_split(
    const unsigned short* __restrict__ Ah, const unsigned short* __restrict__ Al, int lda,
    const unsigned short* __restrict__ Bh, const unsigned short* __restrict__ Bl, int ldb,
    const float* __restrict__ bias,
    float* __restrict__ C, unsigned short* __restrict__ Cb, int ldc,
    int K, int act)
{
    __shared__ unsigned short AsH[128 * 40];
    __shared__ unsigned short AsL[128 * 40];
    __shared__ unsigned short BsH[128 * 40];
    __shared__ unsigned short BsL[128 * 40];
    const int tid = threadIdx.x;
    const int m0 = blockIdx.y * 128, n0 = blockIdx.x * 128;
    const int wave = tid >> 6, lane = tid & 63;
    const int wm = (wave >> 1) * 64, wn = (wave & 1) * 64;
    const int lrow = lane & 15, lk = (lane >> 4) * 8;

    f32x4 acc[4][4];
#pragma unroll
    for (int i = 0; i < 4; ++i)
#pragma unroll
        for (int j = 0; j < 4; ++j) acc[i][j] = (f32x4){0.f, 0.f, 0.f, 0.f};

    for (int k0 = 0; k0 < K; k0 += 32) {
#pragma unroll
        for (int i = 0; i < 2; ++i) {
            int idx = tid + i * 256;        // 0..511
            int rr = idx >> 2, kq = (idx & 3) * 8;
            size_t ao = (size_t)(m0 + rr) * lda + k0 + kq;
            size_t bo = (size_t)(n0 + rr) * ldb + k0 + kq;
            *(uint4*)(&AsH[rr * 40 + kq]) = *(const uint4*)(Ah + ao);
            *(uint4*)(&AsL[rr * 40 + kq]) = *(const uint4*)(Al + ao);
            *(uint4*)(&BsH[rr * 40 + kq]) = *(const uint4*)(Bh + bo);
            *(uint4*)(&BsL[rr * 40 + kq]) = *(const uint4*)(Bl + bo);
        }
        __syncthreads();
        bf16x8 ah[4], al[4], bh[4], bl[4];
#pragma unroll
        for (int i = 0; i < 4; ++i) {
            ah[i] = *(const bf16x8*)(&AsH[(wm + i * 16 + lrow) * 40 + lk]);
            al[i] = *(const bf16x8*)(&AsL[(wm + i * 16 + lrow) * 40 + lk]);
        }
#pragma unroll
        for (int j = 0; j < 4; ++j) {
            bh[j] = *(const bf16x8*)(&BsH[(wn + j * 16 + lrow) * 40 + lk]);
            bl[j] = *(const bf16x8*)(&BsL[(wn + j * 16 + lrow) * 40 + lk]);
        }
#pragma unroll
        for (int i = 0; i < 4; ++i)
#pragma unroll
            for (int j = 0; j < 4; ++j) {
                acc[i][j] = __builtin_amdgcn_mfma_f32_16x16x32_bf16(ah[i], bh[j], acc[i][j], 0, 0, 0);
                acc[i][j] = __builtin_amdgcn_mfma_f32_16x16x32_bf16(ah[i], bl[j], acc[i][j], 0, 0, 0);
                acc[i][j] = __builtin_amdgcn_mfma_f32_16x16x32_bf16(al[i], bh[j], acc[i][j], 0, 0, 0);
            }
        __syncthreads();
    }

    const int crow = m0 + wm + ((lane >> 4) * 4);
    const int ccol = n0 + wn + (lane & 15);
#pragma unroll
    for (int i = 0; i < 4; ++i) {
#pragma unroll
        for (int j = 0; j < 4; ++j) {
            int col = ccol + j * 16;
            float bv = bias[col];
#pragma unroll
            for (int rr = 0; rr < 4; ++rr) {
                int row = crow + i * 16 + rr;
                float v = acc[i][j][rr] + bv;
                if (act == 1) v = tanhf(v);
                if (Cb) Cb[(size_t)row * ldc + col] = f2bf(v);
                else    C [(size_t)row * ldc + col] = v;
            }
        }
    }
}

// --------------------------- persistent GRU --------------------------------
// 16 independent gangs (one per batch) x 16 blocks x 512 threads.
// NO barrier: h element j at step t lives in hslots[t&1][b][j] as
// (tag=t)<<32 | float_bits, written with one relaxed 8B agent atomic.
// Per step: wave 0 polls its 8 slots/lane until tag==t, stages floats into
// LDS (2-deep parity buffer), one __syncthreads, all waves compute.
// Overwrite of a parity slot (t -> t+2) only happens after its writer read
// all of h_{t+1}, which requires every block to have finished step-t reads
// -> no ABA, no deadlock.

__global__ __launch_bounds__(512) void gru_persistent(
    const float* __restrict__ xp,        // (1024,1536) rows = b*64+t
    const float* __restrict__ Whh,       // (1536,512)
    const float* __restrict__ bhh,       // (1536)
    const int*   __restrict__ lengths,   // (16)
    unsigned long long* __restrict__ hslots, // (2,16,512) tagged; zero-init
    unsigned short* __restrict__ cath,   // (1024,1024) cols [0,512)
    unsigned short* __restrict__ catl,
    float* __restrict__ h_last)          // (16,512)
{
    const int bid  = blockIdx.x;
    const int b    = bid >> 4;           // gang = batch
    const int blk  = bid & 15;
    const int tid  = threadIdx.x;
    const int wave = tid >> 6, lane = tid & 63;
    const int j0 = blk * 32 + wave * 4;  // this wave's 4 hidden units
    const int k0 = lane * 8;

    __shared__ float hl[2][512];

    // --- W_hh slice into registers (once): 12 rows x 8 k-elems ---
    float w[12][8];
#pragma unroll
    for (int g = 0; g < 3; ++g)
#pragma unroll
        for (int jj = 0; jj < 4; ++jj) {
            const float* src = Whh + (size_t)(g * 512 + j0 + jj) * Hdim + k0;
            float4 a = *(const float4*)src;
            float4 bq = *(const float4*)(src + 4);
            int r = g * 4 + jj;
            w[r][0] = a.x;  w[r][1] = a.y;  w[r][2] = a.z;  w[r][3] = a.w;
            w[r][4] = bq.x; w[r][5] = bq.y; w[r][6] = bq.z; w[r][7] = bq.w;
        }

    const int j = j0 + (lane & 3);       // output unit for lanes 0..3
    float bh_r = 0.f, bh_z = 0.f, bh_n = 0.f;
    if (lane < 4) {
        bh_r = bhh[j]; bh_z = bhh[512 + j]; bh_n = bhh[1024 + j];
    }
    const int len_b = lengths[b];
    float hprev = 0.f;                   // this lane's own h[b][j] (h0 = 0)

    const size_t PSTR = (size_t)Bdim * Hdim;           // parity stride
    unsigned long long* gslot = hslots + (size_t)b * Hdim;
    const float* xbase = xp + (size_t)b * Tdim * 1536;

    for (int t = 0; t < Tdim; ++t) {
        const int par = t & 1;

        // xp loads are independent of h -> issue early
        float xr = 0.f, xz = 0.f, xn = 0.f;
        if (lane < 4) {
            const float* xrow = xbase + (size_t)t * 1536;
            xr = xrow[j]; xz = xrow[512 + j]; xn = xrow[1024 + j];
        }

        // wave 0: poll tagged slots (tag == t), stage into LDS
        if (wave == 0) {
            const unsigned long long* sl = gslot + (size_t)par * PSTR + k0;
            unsigned long long v[8];
            bool ok;
            do {
#pragma unroll
                for (int q = 0; q < 8; ++q)
                    v[q] = __hip_atomic_load(sl + q, __ATOMIC_RELAXED,
                                             __HIP_MEMORY_SCOPE_AGENT);
                ok = true;
#pragma unroll
                for (int q = 0; q < 8; ++q)
                    ok = ok && ((unsigned)(v[q] >> 32) == (unsigned)t);
            } while (!ok);
#pragma unroll
            for (int q = 0; q < 8; ++q)
                hl[par][k0 + q] = __uint_as_float((unsigned)v[q]);
        }
        __syncthreads();

        float hv[8];
#pragma unroll
        for (int q = 0; q < 8; ++q) hv[q] = hl[par][k0 + q];

        float p[12];
#pragma unroll
        for (int r = 0; r < 12; ++r) {
            float s = 0.f;
#pragma unroll
            for (int k = 0; k < 8; ++k) s += w[r][k] * hv[k];
            p[r] = s;
        }

        // butterfly reduce across 64 lanes
#pragma unroll
        for (int off = 1; off < 64; off <<= 1)
#pragma unroll
            for (int r = 0; r < 12; ++r)
                p[r] += __shfl_xor(p[r], off);

        if (lane < 4) {
            const int jj = lane;
            float hr = p[jj]     + bh_r;
            float hz = p[4 + jj] + bh_z;
            float hn = p[8 + jj] + bh_n;
            float rg = 1.f / (1.f + __expf(-(xr + hr)));
            float zg = 1.f / (1.f + __expf(-(xz + hz)));
            float ng = tanhf(xn + rg * hn);
            float hnew = (1.f - zg) * ng + zg * hprev;
            bool valid = t < len_b;
            float hkeep = valid ? hnew : hprev;
            hprev = hkeep;
            // publish h_{t+1} FIRST (critical path for the whole gang)
            if (t < Tdim - 1) {
                unsigned long long pv =
                    ((unsigned long long)(unsigned)(t + 1) << 32) |
                    (unsigned long long)__float_as_uint(hkeep);
                __hip_atomic_store(gslot + (size_t)((t + 1) & 1) * PSTR + j, pv,
                                   __ATOMIC_RELAXED, __HIP_MEMORY_SCOPE_AGENT);
            } else {
                h_last[b * Hdim + j] = hkeep;
            }
            float y = valid ? hnew : 0.f;
            unsigned short yh = f2bf(y);
            size_t ci = (size_t)(b * Tdim + t) * 1024 + j;
            cath[ci] = yh;
            catl[ci] = f2bf(y - bf2f(yh));
        }
    }
}

// ------------------------------ attention ----------------------------------
// one block per (b,d); writes context to cat cols [512,1024) as hi/lo bf16

__global__ __launch_bounds__(256) void attn_kernel(
    const float* __restrict__ encp,     // (1024,512)
    const float* __restrict__ decp,     // (1024,512)
    const float* __restrict__ enc,      // (16,64,512)
    const float* __restrict__ battn,    // (512)
    const float* __restrict__ vw,       // (512)
    const float* __restrict__ vb,       // (1)
    const int* __restrict__ enc_len,    // (16)
    const int* __restrict__ dec_len,    // (16)
    unsigned short* __restrict__ cath,
    unsigned short* __restrict__ catl)
{
    const int blk = blockIdx.x;
    const int b = blk >> 6, d = blk & 63;
    const int tid = threadIdx.x;
    const size_t obase = (size_t)(b * Tdim + d) * 1024 + 512;

    if (d >= dec_len[b]) {
        for (int h = tid; h < Hdim; h += 256) { cath[obase + h] = 0; catl[obase + h] = 0; }
        return;
    }
    const int Tv = enc_len[b];

    __shared__ float part[64][4];
    __shared__ float a_lds[64];

    const int e = tid >> 2, p = tid & 3;
    float s = 0.f;
    if (e < Tv) {
        const float* ep = encp + (size_t)(b * Tdim + e) * Hdim;
        const float* dp = decp + (size_t)(b * Tdim + d) * Hdim;
        const int g0 = p * 128;
        for (int g = g0; g < g0 + 128; ++g)
            s += vw[g] * tanhf(ep[g] + dp[g] + battn[g]);
    }
    part[e][p] = s;
    __syncthreads();

    if (tid < 64) {
        const int e2 = tid;
        float en = (e2 < Tv) ? (part[e2][0] + part[e2][1] + part[e2][2] + part[e2][3] + vb[0]) : -1e30f;
        float m = en;
#pragma unroll
        for (int off = 32; off; off >>= 1) m = fmaxf(m, __shfl_xor(m, off));
        float ex = (e2 < Tv) ? __expf(en - m) : 0.f;
        float sum = ex;
#pragma unroll
        for (int off = 32; off; off >>= 1) sum += __shfl_xor(sum, off);
        a_lds[e2] = ex / sum;
    }
    __syncthreads();

    const int h = tid * 2;
    float c0 = 0.f, c1 = 0.f;
    for (int e3 = 0; e3 < Tv; ++e3) {
        float a = a_lds[e3];
        float2 ev = *(const float2*)(enc + (size_t)(b * Tdim + e3) * Hdim + h);
        c0 += a * ev.x; c1 += a * ev.y;
    }
    unsigned short h0 = f2bf(c0), h1 = f2bf(c1);
    cath[obase + h]     = h0;  catl[obase + h]     = f2bf(c0 - bf2f(h0));
    cath[obase + h + 1] = h1;  catl[obase + h + 1] = f2bf(c1 - bf2f(h1));
}

// --------------------------- logits bf16 MFMA GEMM -------------------------
// C(1024 x 32000) = A(1024x512 bf16) @ B(32000x512 f32, converted inline)^T
//                   + bias, fp32 out

__global__ __launch_bounds__(256) void gemm_logits(
    const unsigned short* __restrict__ A,
    const float* __restrict__ Bf,
    const float* __restrict__ bias,
    float* __restrict__ C)
{
    const int K = Hdim;
    __shared__ unsigned short As[128 * 40];
    __shared__ unsigned short Bs[128 * 40];
    const int tid = threadIdx.x;
    const int m0 = blockIdx.y * 128, n0 = blockIdx.x * 128;
    const int wave = tid >> 6, lane = tid & 63;
    const int wm = (wave >> 1) * 64, wn = (wave & 1) * 64;
    const int lrow = lane & 15, lk = (lane >> 4) * 8;

    f32x4 acc[4][4];
#pragma unroll
    for (int i = 0; i < 4; ++i)
#pragma unroll
        for (int j = 0; j < 4; ++j) acc[i][j] = (f32x4){0.f, 0.f, 0.f, 0.f};

    for (int k0 = 0; k0 < K; k0 += 32) {
#pragma unroll
        for (int i = 0; i < 2; ++i) {
            int idx = tid + i * 256;        // 0..511
            int rr = idx >> 2, kq = (idx & 3) * 8;
            *(uint4*)(&As[rr * 40 + kq]) = *(const uint4*)(A + (size_t)(m0 + rr) * K + k0 + kq);
            const float* bp = Bf + (size_t)(n0 + rr) * K + k0 + kq;
            float4 b0 = *(const float4*)bp;
            float4 b1 = *(const float4*)(bp + 4);
            unsigned short hb[8] = {f2bf(b0.x), f2bf(b0.y), f2bf(b0.z), f2bf(b0.w),
                                    f2bf(b1.x), f2bf(b1.y), f2bf(b1.z), f2bf(b1.w)};
            *(uint4*)(&Bs[rr * 40 + kq]) = *(const uint4*)hb;
        }
        __syncthreads();
        bf16x8 af[4], bf[4];
#pragma unroll
        for (int i = 0; i < 4; ++i) af[i] = *(const bf16x8*)(&As[(wm + i * 16 + lrow) * 40 + lk]);
#pragma unroll
        for (int j = 0; j < 4; ++j) bf[j] = *(const bf16x8*)(&Bs[(wn + j * 16 + lrow) * 40 + lk]);
#pragma unroll
        for (int i = 0; i < 4; ++i)
#pragma unroll
            for (int j = 0; j < 4; ++j)
                acc[i][j] = __builtin_amdgcn_mfma_f32_16x16x32_bf16(af[i], bf[j], acc[i][j], 0, 0, 0);
        __syncthreads();
    }

    const int crow = m0 + wm + ((lane >> 4) * 4);
    const int ccol = n0 + wn + (lane & 15);
#pragma unroll
    for (int i = 0; i < 4; ++i) {
#pragma unroll
        for (int j = 0; j < 4; ++j) {
            int col = ccol + j * 16;
            float bv = bias[col];
#pragma unroll
            for (int rr = 0; rr < 4; ++rr) {
                int row = crow + i * 16 + rr;
                C[(size_t)row * Vdim + col] = acc[i][j][rr] + bv;
            }
        }
    }
}

// ------------------------------- launcher ----------------------------------

extern "C" void kernel_launch(void* const* d_in, const int* in_sizes, int n_in,
                              void* d_out, int out_size, void* d_ws, size_t ws_size,
                              hipStream_t stream) {
    (void)in_sizes; (void)n_in; (void)out_size; (void)ws_size;

    const float* input_seqs  = (const float*)d_in[0];
    const int*   input_len   = (const int*)  d_in[1];
    const float* enc_out     = (const float*)d_in[2];
    const int*   enc_len     = (const int*)  d_in[3];
    const float* W_ih        = (const float*)d_in[4];
    const float* W_hh        = (const float*)d_in[5];
    const float* b_ih        = (const float*)d_in[6];
    const float* b_hh        = (const float*)d_in[7];
    const float* W_attn      = (const float*)d_in[8];
    const float* b_attn      = (const float*)d_in[9];
    const float* v_w         = (const float*)d_in[10];
    const float* v_b         = (const float*)d_in[11];
    const float* W_dense     = (const float*)d_in[12];
    const float* b_dense     = (const float*)d_in[13];
    const float* W_out       = (const float*)d_in[14];
    const float* b_out       = (const float*)d_in[15];

    float* logits = (float*)d_out;                        // (1024, 32000)
    float* h_last = (float*)d_out + (size_t)BT * Vdim;    // (16, 512)

    // ---- workspace layout ----
    float* ws    = (float*)d_ws;
    float* xp    = ws;                         // 1572864 f
    float* encp  = xp   + 1572864;             // 524288 f
    float* decp  = encp + 524288;              // 524288 f
    unsigned long long* hslots = (unsigned long long*)(decp + 524288); // 16384 u64
    float* zbias = (float*)(hslots + 16384);   // 512 f (contiguous after hslots)
    unsigned short* U0 = (unsigned short*)(zbias + 512);
    unsigned short* inp_h   = U0;               // 524288
    unsigned short* inp_l   = U0 + 524288;      // 524288
    unsigned short* Wih_h   = U0 + 1048576;     // 786432
    unsigned short* Wih_l   = U0 + 1835008;     // 786432
    unsigned short* Wattn_h = U0 + 2621440;     // 524288
    unsigned short* Wattn_l = U0 + 3145728;     // 524288
    unsigned short* Wden_h  = U0 + 3670016;     // 524288
    unsigned short* Wden_l  = U0 + 4194304;     // 524288
    unsigned short* enc_h   = U0 + 4718592;     // 524288
    unsigned short* enc_l   = U0 + 5242880;     // 524288
    // cat hi/lo alias the inp/Wih splits (dead after x_proj):
    unsigned short* cath = U0;                  // 1048576 (1024x1024)
    unsigned short* catl = U0 + 1048576;        // 1048576
    // dense_bf aliases encp (dead after attn):
    unsigned short* dense_bf = (unsigned short*)encp;   // 524288

    // 1. merged preprocessing: zero hslots+zbias, all hi/lo splits
    preproc_kernel<<<2849, 256, 0, stream>>>(
        input_seqs, W_ih, W_attn, W_dense, enc_out,
        (float*)hslots,
        inp_h, inp_l, Wih_h, Wih_l, Wattn_h, Wattn_l,
        Wden_h, Wden_l, enc_h, enc_l);

    // 2. x_proj = input_seqs @ W_ih^T + b_ih   (1024 x 1536, K=512)
    gemm_split<<<dim3(1536 / 128, BT / 128), 256, 0, stream>>>(
        inp_h, inp_l, Hdim, Wih_h, Wih_l, Hdim, b_ih, xp, nullptr, 1536, Hdim, 0);

    // 3. enc_p = enc @ We^T  (We = W_attn[:, :512], ldb=1024), no bias
    gemm_split<<<dim3(Hdim / 128, BT / 128), 256, 0, stream>>>(
        enc_h, enc_l, Hdim, Wattn_h, Wattn_l, 1024, zbias, encp, nullptr, Hdim, Hdim, 0);

    // 4. GRU (16 per-batch gangs x 16 blocks x 512 thr; tagged-slot exchange,
    //    no barrier; writes cat cols [0,512) as hi/lo bf16, h_last)
    gru_persistent<<<Bdim * GANG_BLOCKS, 512, 0, stream>>>(
        xp, W_hh, b_hh, input_len, hslots, cath, catl, h_last);

    // 5. dec_p = dec_out @ Wd^T (A = cat[:, :512] hi/lo, lda=1024), no bias
    gemm_split<<<dim3(Hdim / 128, BT / 128), 256, 0, stream>>>(
        cath, catl, 1024, Wattn_h + 512, Wattn_l + 512, 1024, zbias, decp, nullptr, Hdim, Hdim, 0);

    // 6. attention -> cat cols [512,1024) hi/lo bf16
    attn_kernel<<<BT, 256, 0, stream>>>(encp, decp, enc_out, b_attn, v_w, v_b,
                                        enc_len, input_len, cath, catl);

    // 7. dense = tanh(cat @ W_dense^T + b_dense) -> bf16 directly (K=1024)
    gemm_split<<<dim3(Hdim / 128, BT / 128), 256, 0, stream>>>(
        cath, catl, 1024, Wden_h, Wden_l, 1024, b_dense, nullptr, dense_bf, Hdim, 1024, 1);

    // 8. logits = dense @ W_out^T + b_out  (1024 x 32000, K=512, inline cvt)
    gemm_logits<<<dim3(Vdim / 128, BT / 128), 256, 0, stream>>>(
        dense_bf, W_out, b_out, logits);
}